// Round 23
// baseline (129.464 us; speedup 1.0000x reference)
//
#include <hip/hip_runtime.h>
#include <hip/hip_bf16.h>

#define NH    12
#define HD    64
#define NTOK  1024
#define BATCH 8
#define DM    768

typedef short  short8  __attribute__((ext_vector_type(8)));
typedef float  f32x4   __attribute__((ext_vector_type(4)));
typedef float  f32x16  __attribute__((ext_vector_type(16)));
typedef unsigned short ushort8 __attribute__((ext_vector_type(8)));

// sqrt(0.125 * log2(e)) — pre-scales vn so QK^T yields CS*cos directly
#define SQRT_CS 0.42466056f

__device__ __forceinline__ ushort f2bf(float f) {
    union { float f; unsigned u; } x; x.f = f;
    unsigned r = x.u + 0x7FFF + ((x.u >> 16) & 1);   // RNE
    return (ushort)(r >> 16);
}
__device__ __forceinline__ float bf2f(ushort h) {
    union { unsigned u; float f; } x; x.u = ((unsigned)h) << 16;
    return x.f;
}
__device__ __forceinline__ void gl_lds16f(const float* g, char* l) {
    __builtin_amdgcn_global_load_lds(
        (const __attribute__((address_space(1))) unsigned int*)g,
        (__attribute__((address_space(3))) unsigned int*)l, 16, 0, 0);
}
__device__ __forceinline__ void gl_lds16u(const ushort* g, char* l) {
    __builtin_amdgcn_global_load_lds(
        (const __attribute__((address_space(1))) unsigned int*)g,
        (__attribute__((address_space(3))) unsigned int*)l, 16, 0, 0);
}
__device__ __forceinline__ f32x16 mfma32(short8 a, short8 b, f32x16 c) {
    return __builtin_amdgcn_mfma_f32_32x32x16_bf16(a, b, c, 0, 0, 0);
}

// in-register split: 8 fp32 (two uint4) -> hi bf16x8 + lo bf16x8 (RNE, bit-
// identical to the split kernels: hi = bf16(x), lo = bf16(x - hi)).
__device__ __forceinline__ void split8(uint4 c0, uint4 c1,
                                       short8& hi8, short8& lo8) {
    const unsigned xs[8] = {c0.x, c0.y, c0.z, c0.w, c1.x, c1.y, c1.z, c1.w};
    union { unsigned u[4]; short8 s; } H, L;
    #pragma unroll
    for (int j = 0; j < 4; ++j) {
        float a0 = __uint_as_float(xs[2 * j]);
        float a1 = __uint_as_float(xs[2 * j + 1]);
        unsigned hp;
        asm("v_cvt_pk_bf16_f32 %0, %1, %2" : "=v"(hp) : "v"(a0), "v"(a1));
        float l0 = a0 - __uint_as_float(hp << 16);
        float l1 = a1 - __uint_as_float(hp & 0xFFFF0000u);
        unsigned lp;
        asm("v_cvt_pk_bf16_f32 %0, %1, %2" : "=v"(lp) : "v"(l0), "v"(l1));
        H.u[j] = hp; L.u[j] = lp;
    }
    hi8 = H.s; lo8 = L.s;
}

// ---------------------------------------------------------------------------
// split_w: w -> (hi, lo) bf16. Tiny (2.25 MB traffic).
// ---------------------------------------------------------------------------
__global__ __launch_bounds__(256) void split_w_kernel(
    const float* __restrict__ src, ushort* __restrict__ hi, ushort* __restrict__ lo)
{
    int t = blockIdx.x * 256 + threadIdx.x;       // 73728 threads
    if (t >= (DM * DM) / 8) return;
    const float* s = src + (size_t)t * 8;
    float4 x0 = *(const float4*)s, x1 = *(const float4*)(s + 4);
    float xs[8] = {x0.x, x0.y, x0.z, x0.w, x1.x, x1.y, x1.z, x1.w};
    ushort8 h8, l8;
    #pragma unroll
    for (int j = 0; j < 8; ++j) {
        ushort h = f2bf(xs[j]);
        h8[j] = h;
        l8[j] = f2bf(xs[j] - bf2f(h));
    }
    size_t o = (size_t)t * 8;
    *(ushort8*)(hi + o) = h8;
    *(ushort8*)(lo + o) = l8;
}

// ---------------------------------------------------------------------------
// vproj (hybrid split + 2-phase dbuf, round-19 version — best measured).
// ---------------------------------------------------------------------------
__global__ __launch_bounds__(256) void vproj_mfma_kernel(
    const float* __restrict__ qf,
    const ushort* __restrict__ wh, const ushort* __restrict__ wl,
    ushort* __restrict__ vn, ushort* __restrict__ vt)
{
    __shared__ __align__(16) char smem[49152];   // 2 x 24 KB
    const int bid = blockIdx.x;                  // 0..767
    const int xcd = bid & 7, idx = bid >> 3;     // idx 0..95
    const int mbl = idx & 7, hh = idx >> 3;      // hh 0..11 (head)
    const int mb  = xcd * 8 + mbl;               // 0..63 row-panel
    const int b   = mb >> 3;
    const int nr0 = (mb & 7) * 128;
    const int n0  = hh * 64;

    const int tid = threadIdx.x, wv = tid >> 6, l = tid & 63;
    const int ln  = l & 31, half = l >> 5;

    f32x16 acc[2] = {};

    const int wsel = wv & 1;
    #define STAGE(kt_) do {                                                    \
        char* bufB = smem + ((kt_) & 1) * 24576;                               \
        if (wv < 2) {                                                          \
            _Pragma("unroll")                                                  \
            for (int p = 0; p < 8; ++p) {                                      \
                int chunk = wsel * 512 + p * 64 + l;                           \
                int r = chunk >> 3, s = chunk & 7;                             \
                int c = s ^ (r & 7);                                           \
                gl_lds16f(qf + ((size_t)((nr0 + r) * 8 + b)) * 768             \
                              + (kt_) * 32 + c * 4,                            \
                          bufB + chunk * 16);                                  \
            }                                                                  \
        } else {                                                               \
            _Pragma("unroll")                                                  \
            for (int p = 0; p < 4; ++p) {                                      \
                int chunk = wsel * 256 + p * 64 + l;                           \
                int r = chunk >> 3, s = chunk & 7;                             \
                int c = s ^ (r & 7);                                           \
                const ushort* src = (c < 4)                                    \
                    ? wh + (size_t)(n0 + r) * 768 + (kt_) * 32 + c * 8         \
                    : wl + (size_t)(n0 + r) * 768 + (kt_) * 32 + (c & 3) * 8;  \
                gl_lds16u(src, bufB + 16384 + chunk * 16);                     \
            }                                                                  \
        }                                                                      \
    } while (0)

    STAGE(0);
    __syncthreads();

    for (int kt = 0; kt < 24; ++kt) {
        if (kt + 1 < 24) STAGE(kt + 1);           // issue early: loads fly
        const char*   Ab = smem + (kt & 1) * 24576;
        const ushort* Bb = (const ushort*)(Ab + 16384);

        #pragma unroll
        for (int ks = 0; ks < 2; ++ks) {
            const int cc = ks * 2 + half;         // bf16 k-chunk 0..3
            const int ra = wv * 32 + ln;
            uint4 a0 = *(const uint4*)(Ab + ra * 128 + (((cc * 2)     ^ (ra & 7)) * 16));
            uint4 a1 = *(const uint4*)(Ab + ra * 128 + (((cc * 2 + 1) ^ (ra & 7)) * 16));
            short8 a_h, a_l;
            split8(a0, a1, a_h, a_l);
            short8 b_h[2], b_l[2];
            #pragma unroll
            for (int ni = 0; ni < 2; ++ni) {
                int rb = ni * 32 + ln;
                b_h[ni] = *(const short8*)(Bb + rb * 64 + ((cc       ^ (rb & 7)) * 8));
                b_l[ni] = *(const short8*)(Bb + rb * 64 + (((cc + 4) ^ (rb & 7)) * 8));
            }
            #pragma unroll
            for (int ni = 0; ni < 2; ++ni) {
                acc[ni] = mfma32(a_h, b_h[ni], acc[ni]);
                acc[ni] = mfma32(a_h, b_l[ni], acc[ni]);
                acc[ni] = mfma32(a_l, b_h[ni], acc[ni]);
            }
        }
        __syncthreads();                          // reads done + next stage landed
    }
    #undef STAGE

    // ---- epilogue: C tile -> LDS [128][68] f32, norms, vn + vt ----
    float* Ct = (float*)smem;                     // 128*68*4 = 34816 B
    #pragma unroll
    for (int ni = 0; ni < 2; ++ni)
        #pragma unroll
        for (int i = 0; i < 16; ++i) {
            int row = wv * 32 + (i & 3) + 8 * (i >> 2) + 4 * half;
            Ct[row * 68 + ni * 32 + ln] = acc[ni][i];
        }
    __syncthreads();

    const int bhn = b * NH + hh;
    {   // vn: thread t -> row t>>1, 32-col part t&1 (pair-reduce via shfl)
        int r = tid >> 1, part = tid & 1;
        const float* src = Ct + r * 68 + part * 32;
        float ss = 0.f;
        #pragma unroll
        for (int j = 0; j < 8; ++j) {
            float4 v4 = *(const float4*)(src + j * 4);
            ss += v4.x * v4.x + v4.y * v4.y + v4.z * v4.z + v4.w * v4.w;
        }
        ss += __shfl_xor(ss, 1);
        float rn = rsqrtf(ss) * SQRT_CS;          // fold softmax scale into vn
        ushort* dst = vn + ((size_t)bhn * NTOK + nr0 + r) * HD + part * 32;
        #pragma unroll
        for (int q8 = 0; q8 < 4; ++q8) {
            float4 u0 = *(const float4*)(src + q8 * 8);
            float4 u1 = *(const float4*)(src + q8 * 8 + 4);
            ushort8 o;
            o[0] = f2bf(u0.x * rn); o[1] = f2bf(u0.y * rn);
            o[2] = f2bf(u0.z * rn); o[3] = f2bf(u0.w * rn);
            o[4] = f2bf(u1.x * rn); o[5] = f2bf(u1.y * rn);
            o[6] = f2bf(u1.z * rn); o[7] = f2bf(u1.w * rn);
            *(ushort8*)(dst + q8 * 8) = o;
        }
    }
    {   // vt: thread t -> col d = t&63, 32-row segment seg = t>>6
        int d = tid & 63, seg = tid >> 6;
        ushort* dst = vt + ((size_t)bhn * HD + d) * NTOK + nr0 + seg * 32;
        #pragma unroll
        for (int q8 = 0; q8 < 4; ++q8) {
            ushort8 o;
            #pragma unroll
            for (int j = 0; j < 8; ++j)
                o[j] = f2bf(Ct[(seg * 32 + q8 * 8 + j) * 68 + d]);
            *(ushort8*)(dst + q8 * 8) = o;
        }
    }
}

// ---------------------------------------------------------------------------
// Fallback vproj (all-in-register split, single-buffered) if ws too small.
// ---------------------------------------------------------------------------
__global__ __launch_bounds__(256) void vproj_mfma_irs_kernel(
    const float* __restrict__ qf, const float* __restrict__ wf,
    ushort* __restrict__ vn, ushort* __restrict__ vt)
{
    __shared__ __align__(16) char smem[49152];
    char* Ae = smem;
    char* Ao = smem + 16384;
    char* Be = smem + 32768;
    char* Bo = smem + 40960;

    const int bid = blockIdx.x;
    const int xcd = bid & 7, idx = bid >> 3;
    const int mbl = idx & 7, hh = idx >> 3;
    const int mb  = xcd * 8 + mbl;
    const int b   = mb >> 3;
    const int nr0 = (mb & 7) * 128;
    const int n0  = hh * 64;

    const int tid = threadIdx.x, wv = tid >> 6, l = tid & 63;
    const int ln  = l & 31, half = l >> 5;

    f32x16 acc[2] = {};

    for (int kt = 0; kt < 12; ++kt) {
        __syncthreads();
        if (wv < 2) {
            char* dstT = wv ? Ao : Ae;
            const int kofs = kt * 64 + wv * 32;
            #pragma unroll
            for (int p = 0; p < 16; ++p) {
                int chunk = p * 64 + l;
                int r = chunk >> 3, c = chunk & 7;
                int csrc = c ^ (r & 7);
                gl_lds16f(qf + ((size_t)((nr0 + r) * 8 + b)) * 768 + kofs + csrc * 4,
                          dstT + p * 1024);
            }
        } else {
            char* dstT = (wv == 3) ? Bo : Be;
            const int kofs = kt * 64 + (wv == 3 ? 32 : 0);
            #pragma unroll
            for (int p = 0; p < 8; ++p) {
                int chunk = p * 64 + l;
                int r = chunk >> 3, c = chunk & 7;
                int csrc = c ^ (r & 7);
                gl_lds16f(wf + (size_t)(n0 + r) * 768 + kofs + csrc * 4,
                          dstT + p * 1024);
            }
        }
        __syncthreads();

        #pragma unroll
        for (int ks = 0; ks < 4; ++ks) {
            const int cc  = ks * 2 + half;
            const int cc2 = (cc & 3) * 2;
            const int ra  = wv * 32 + ln;
            const char* At = (cc < 4) ? Ae : Ao;
            uint4 a0 = *(const uint4*)(At + ra * 128 + ((cc2 ^ (ra & 7)) * 16));
            uint4 a1 = *(const uint4*)(At + ra * 128 + (((cc2 + 1) ^ (ra & 7)) * 16));
            short8 a_h, a_l;
            split8(a0, a1, a_h, a_l);
            short8 b_h[2], b_l[2];
            const char* Bt = (cc < 4) ? Be : Bo;
            #pragma unroll
            for (int ni = 0; ni < 2; ++ni) {
                int rb = ni * 32 + ln;
                uint4 b0 = *(const uint4*)(Bt + rb * 128 + ((cc2 ^ (rb & 7)) * 16));
                uint4 b1 = *(const uint4*)(Bt + rb * 128 + (((cc2 + 1) ^ (rb & 7)) * 16));
                split8(b0, b1, b_h[ni], b_l[ni]);
            }
            #pragma unroll
            for (int ni = 0; ni < 2; ++ni) {
                acc[ni] = mfma32(a_h, b_h[ni], acc[ni]);
                acc[ni] = mfma32(a_h, b_l[ni], acc[ni]);
                acc[ni] = mfma32(a_l, b_h[ni], acc[ni]);
            }
        }
    }

    __syncthreads();
    float* Ct = (float*)smem;
    #pragma unroll
    for (int ni = 0; ni < 2; ++ni)
        #pragma unroll
        for (int i = 0; i < 16; ++i) {
            int row = wv * 32 + (i & 3) + 8 * (i >> 2) + 4 * half;
            Ct[row * 68 + ni * 32 + ln] = acc[ni][i];
        }
    __syncthreads();

    const int bhn = b * NH + hh;
    {
        int r = tid >> 1, part = tid & 1;
        const float* src = Ct + r * 68 + part * 32;
        float ss = 0.f;
        #pragma unroll
        for (int j = 0; j < 8; ++j) {
            float4 v4 = *(const float4*)(src + j * 4);
            ss += v4.x * v4.x + v4.y * v4.y + v4.z * v4.z + v4.w * v4.w;
        }
        ss += __shfl_xor(ss, 1);
        float rn = rsqrtf(ss) * SQRT_CS;
        ushort* dst = vn + ((size_t)bhn * NTOK + nr0 + r) * HD + part * 32;
        #pragma unroll
        for (int q8 = 0; q8 < 4; ++q8) {
            float4 u0 = *(const float4*)(src + q8 * 8);
            float4 u1 = *(const float4*)(src + q8 * 8 + 4);
            ushort8 o;
            o[0] = f2bf(u0.x * rn); o[1] = f2bf(u0.y * rn);
            o[2] = f2bf(u0.z * rn); o[3] = f2bf(u0.w * rn);
            o[4] = f2bf(u1.x * rn); o[5] = f2bf(u1.y * rn);
            o[6] = f2bf(u1.z * rn); o[7] = f2bf(u1.w * rn);
            *(ushort8*)(dst + q8 * 8) = o;
        }
    }
    {
        int d = tid & 63, seg = tid >> 6;
        ushort* dst = vt + ((size_t)bhn * HD + d) * NTOK + nr0 + seg * 32;
        #pragma unroll
        for (int q8 = 0; q8 < 4; ++q8) {
            ushort8 o;
            #pragma unroll
            for (int j = 0; j < 8; ++j)
                o[j] = f2bf(Ct[(seg * 32 + q8 * 8 + j) * 68 + d]);
            *(ushort8*)(dst + q8 * 8) = o;
        }
    }
}

// ---------------------------------------------------------------------------
// Kernel 2: flash attention — 2-WAVE blocks (128 thr), Q-tile 64, grid 1536,
// round-11 retry with the spill bug fixed: NO waves-per-EU bound (natural
// VGPR, no scratch). Body = proven round-20 single-barrier dbuf + group-
// pipelined softmax/PV. 32 KB LDS -> ~5 blocks/CU = 5 independent barrier
// domains (vs 3). Per-wave arithmetic identical -> bit-identical output.
// XCD decode: all 16 q-blocks of a bh share bid%8.
// ---------------------------------------------------------------------------
__global__ __launch_bounds__(128) void attn_kernel(
    const ushort* __restrict__ vn, const ushort* __restrict__ vt,
    float* __restrict__ out)
{
    __shared__ __align__(16) ushort Klds[2][64 * 64];   // [kv][d], swizzled
    __shared__ __align__(16) ushort Vlds[2][64 * 64];   // [d][kv], swizzled
    const int sblk = blockIdx.x;                 // 0..1535
    const int tt   = sblk >> 3;                  // 0..191
    const int bh   = (sblk & 7) + 8 * (tt >> 4); // XCD(bid%8) == bh%8
    const int q0   = (tt & 15) * 64;
    const int tid = threadIdx.x;                 // 0..127
    const int wv  = tid >> 6;                    // 0..1
    const int l   = tid & 63;
    const int ql  = l & 31;          // q column (one q-row per lane)
    const int h   = l >> 5;          // half

    const ushort* vb  = vn + (size_t)bh * NTOK * HD;
    const ushort* vtb = vt + (size_t)bh * HD * NTOK;

    short8 qB[4];
    {
        int qrow = q0 + wv * 32 + ql;
        #pragma unroll
        for (int ks = 0; ks < 4; ++ks)
            qB[ks] = *(const short8*)(vb + (size_t)qrow * HD + ks * 16 + h * 8);
    }

    // staging: 512 chunks per K (and V) tile; 128 threads -> 4 chunks each.
    // rows r = sr + 16p; (sr+16p)&7 == sr&7 so the swizzle slot is constant.
    const int sr  = tid >> 3;                    // 0..15
    const int sc  = tid & 7;
    const int slt = (sc ^ (sr & 7)) * 8;
    uint4 kreg[4], vreg[4];

    f32x16 oT[2] = {};
    float l_acc = 0.f;

    #pragma unroll
    for (int p = 0; p < 4; ++p) {
        int r = sr + p * 16;
        kreg[p] = *(const uint4*)(vb + (size_t)r * HD + sc * 8);
        vreg[p] = *(const uint4*)(vtb + (size_t)r * NTOK + sc * 8);
    }
    #pragma unroll
    for (int p = 0; p < 4; ++p) {
        int r = sr + p * 16;
        *(uint4*)(&Klds[0][0] + r * 64 + slt) = kreg[p];
        *(uint4*)(&Vlds[0][0] + r * 64 + slt) = vreg[p];
    }
    __syncthreads();

    for (int kt = 0; kt < NTOK / 64; ++kt) {
        const int cur = kt & 1;
        const ushort* Kb = &Klds[cur][0];
        const ushort* Vb = &Vlds[cur][0];

        // T14: issue next tile's global loads early (land during compute)
        if (kt < NTOK / 64 - 1) {
            int kb = (kt + 1) * 64;
            #pragma unroll
            for (int p = 0; p < 4; ++p) {
                int r = sr + p * 16;
                kreg[p] = *(const uint4*)(vb + (size_t)(kb + r) * HD + sc * 8);
                vreg[p] = *(const uint4*)(vtb + (size_t)r * NTOK + kb + sc * 8);
            }
        }

        // QK^T: both 32-kv groups (chains interleave freely)
        f32x16 st[2] = {};
        #pragma unroll
        for (int ks = 0; ks < 4; ++ks) {
            int so = ((2 * ks + h) ^ (ql & 7)) * 8;
            short8 k0 = *(const short8*)(Kb + ql * 64 + so);
            short8 k1 = *(const short8*)(Kb + (32 + ql) * 64 + so);
            st[0] = mfma32(k0, qB[ks], st[0]);
            st[1] = mfma32(k1, qB[ks], st[1]);
        }

        // per group: exp2 -> sum -> pack -> PV
        #pragma unroll
        for (int g = 0; g < 2; ++g) {
            #pragma unroll
            for (int i = 0; i < 16; ++i)
                st[g][i] = __builtin_amdgcn_exp2f(st[g][i]);

            float ts[8];
            #pragma unroll
            for (int i = 0; i < 8; ++i) ts[i] = st[g][i] + st[g][i + 8];
            #pragma unroll
            for (int s = 4; s >= 1; s >>= 1)
                #pragma unroll
                for (int i = 0; i < s; ++i) ts[i] += ts[i + s];
            l_acc += ts[0];

            unsigned pb2[4][2];
            #pragma unroll
            for (int t = 0; t < 4; ++t)
                #pragma unroll
                for (int u = 0; u < 2; ++u)
                    asm("v_cvt_pk_bf16_f32 %0, %1, %2"
                        : "=v"(pb2[t][u])
                        : "v"(st[g][4 * t + 2 * u]), "v"(st[g][4 * t + 2 * u + 1]));

            #pragma unroll
            for (int sp = 0; sp < 2; ++sp) {
                const int s = g * 2 + sp;
                unsigned x0 = pb2[2 * sp][0], y0 = pb2[2 * sp + 1][0];
                unsigned x1 = pb2[2 * sp][1], y1 = pb2[2 * sp + 1][1];
                asm volatile("v_permlane32_swap_b32 %0, %1" : "+v"(x0), "+v"(y0));
                asm volatile("v_permlane32_swap_b32 %0, %1" : "+v"(x1), "+v"(y1));
                union { unsigned u[4]; short8 s8; } pb;
                pb.u[0] = x0; pb.u[1] = x1; pb.u[2] = y0; pb.u[3] = y1;
                int so = ((2 * s + h) ^ (ql & 7)) * 8;
                short8 v0 = *(const short8*)(Vb + ql * 64 + so);
                short8 v1 = *(const short8*)(Vb + (32 + ql) * 64 + so);
                oT[0] = mfma32(v0, pb.s8, oT[0]);
                oT[1] = mfma32(v1, pb.s8, oT[1]);
            }
        }

        // write next tile into the alternate buffer, ONE barrier per tile
        if (kt < NTOK / 64 - 1) {
            #pragma unroll
            for (int p = 0; p < 4; ++p) {
                int r = sr + p * 16;
                *(uint4*)(&Klds[cur ^ 1][0] + r * 64 + slt) = kreg[p];
                *(uint4*)(&Vlds[cur ^ 1][0] + r * 64 + slt) = vreg[p];
            }
            __syncthreads();
        }
    }

    const int b = bh / NH, hh = bh % NH;
    float lsum = l_acc + __shfl_xor(l_acc, 32);
    const float inv = 1.f / lsum;
    int n = q0 + wv * 32 + ql;
    float* orow = out + ((size_t)n * BATCH + b) * DM + hh * HD;
    #pragma unroll
    for (int dm = 0; dm < 2; ++dm)
        #pragma unroll
        for (int t = 0; t < 4; ++t) {
            float4 val = make_float4(oT[dm][4 * t] * inv, oT[dm][4 * t + 1] * inv,
                                     oT[dm][4 * t + 2] * inv, oT[dm][4 * t + 3] * inv);
            *(float4*)(orow + dm * 32 + t * 8 + h * 4) = val;
        }
}

extern "C" void kernel_launch(void* const* d_in, const int* in_sizes, int n_in,
                              void* d_out, int out_size, void* d_ws, size_t ws_size,
                              hipStream_t stream) {
    const float* q = (const float*)d_in[0];   // [1024, 8, 768]
    const float* w = (const float*)d_in[1];   // [768, 768]
    float* out = (float*)d_out;               // [1024, 8, 768]

    const size_t VE = (size_t)NH * BATCH * NTOK * HD;  // 6,291,456
    const size_t WE = (size_t)DM * DM;                 //   589,824
    ushort* vn = (ushort*)d_ws;                        // [96][1024][64] bf16
    ushort* vt = vn + VE;                              // [96][64][1024] bf16
    ushort* wh = vt + VE;
    ushort* wl = wh + WE;
    size_t need = (2 * VE + 2 * WE) * sizeof(ushort);

    if (ws_size >= need) {
        split_w_kernel<<<(WE / 8 + 255) / 256, 256, 0, stream>>>(w, wh, wl);
        vproj_mfma_kernel<<<768, 256, 0, stream>>>(q, wh, wl, vn, vt);
    } else {
        vproj_mfma_irs_kernel<<<768, 256, 0, stream>>>(q, w, vn, vt);
    }
    attn_kernel<<<16 * BATCH * NH, 128, 0, stream>>>(vn, vt, out);
}

// Round 24
// 89.357 us; speedup vs baseline: 1.4488x; 1.4488x over previous
//
#include <hip/hip_runtime.h>
#include <hip/hip_bf16.h>

#define NH    12
#define HD    64
#define NTOK  1024
#define BATCH 8
#define DM    768

typedef short  short8  __attribute__((ext_vector_type(8)));
typedef float  f32x4   __attribute__((ext_vector_type(4)));
typedef float  f32x16  __attribute__((ext_vector_type(16)));
typedef unsigned short ushort8 __attribute__((ext_vector_type(8)));

// sqrt(0.125 * log2(e)) — pre-scales vn so QK^T yields CS*cos directly
#define SQRT_CS 0.42466056f

__device__ __forceinline__ ushort f2bf(float f) {
    union { float f; unsigned u; } x; x.f = f;
    unsigned r = x.u + 0x7FFF + ((x.u >> 16) & 1);   // RNE
    return (ushort)(r >> 16);
}
__device__ __forceinline__ float bf2f(ushort h) {
    union { unsigned u; float f; } x; x.u = ((unsigned)h) << 16;
    return x.f;
}
__device__ __forceinline__ void gl_lds16f(const float* g, char* l) {
    __builtin_amdgcn_global_load_lds(
        (const __attribute__((address_space(1))) unsigned int*)g,
        (__attribute__((address_space(3))) unsigned int*)l, 16, 0, 0);
}
__device__ __forceinline__ void gl_lds16u(const ushort* g, char* l) {
    __builtin_amdgcn_global_load_lds(
        (const __attribute__((address_space(1))) unsigned int*)g,
        (__attribute__((address_space(3))) unsigned int*)l, 16, 0, 0);
}
__device__ __forceinline__ f32x16 mfma32(short8 a, short8 b, f32x16 c) {
    return __builtin_amdgcn_mfma_f32_32x32x16_bf16(a, b, c, 0, 0, 0);
}

// in-register split: 8 fp32 (two uint4) -> hi bf16x8 + lo bf16x8 (RNE, bit-
// identical to the split kernels: hi = bf16(x), lo = bf16(x - hi)).
__device__ __forceinline__ void split8(uint4 c0, uint4 c1,
                                       short8& hi8, short8& lo8) {
    const unsigned xs[8] = {c0.x, c0.y, c0.z, c0.w, c1.x, c1.y, c1.z, c1.w};
    union { unsigned u[4]; short8 s; } H, L;
    #pragma unroll
    for (int j = 0; j < 4; ++j) {
        float a0 = __uint_as_float(xs[2 * j]);
        float a1 = __uint_as_float(xs[2 * j + 1]);
        unsigned hp;
        asm("v_cvt_pk_bf16_f32 %0, %1, %2" : "=v"(hp) : "v"(a0), "v"(a1));
        float l0 = a0 - __uint_as_float(hp << 16);
        float l1 = a1 - __uint_as_float(hp & 0xFFFF0000u);
        unsigned lp;
        asm("v_cvt_pk_bf16_f32 %0, %1, %2" : "=v"(lp) : "v"(l0), "v"(l1));
        H.u[j] = hp; L.u[j] = lp;
    }
    hi8 = H.s; lo8 = L.s;
}

// ---------------------------------------------------------------------------
// split_w: w -> (hi, lo) bf16. Tiny (2.25 MB traffic).
// ---------------------------------------------------------------------------
__global__ __launch_bounds__(256) void split_w_kernel(
    const float* __restrict__ src, ushort* __restrict__ hi, ushort* __restrict__ lo)
{
    int t = blockIdx.x * 256 + threadIdx.x;       // 73728 threads
    if (t >= (DM * DM) / 8) return;
    const float* s = src + (size_t)t * 8;
    float4 x0 = *(const float4*)s, x1 = *(const float4*)(s + 4);
    float xs[8] = {x0.x, x0.y, x0.z, x0.w, x1.x, x1.y, x1.z, x1.w};
    ushort8 h8, l8;
    #pragma unroll
    for (int j = 0; j < 8; ++j) {
        ushort h = f2bf(xs[j]);
        h8[j] = h;
        l8[j] = f2bf(xs[j] - bf2f(h));
    }
    size_t o = (size_t)t * 8;
    *(ushort8*)(hi + o) = h8;
    *(ushort8*)(lo + o) = l8;
}

// ---------------------------------------------------------------------------
// vproj (hybrid split + 2-phase dbuf, round-19 version — best measured).
// ---------------------------------------------------------------------------
__global__ __launch_bounds__(256) void vproj_mfma_kernel(
    const float* __restrict__ qf,
    const ushort* __restrict__ wh, const ushort* __restrict__ wl,
    ushort* __restrict__ vn, ushort* __restrict__ vt)
{
    __shared__ __align__(16) char smem[49152];   // 2 x 24 KB
    const int bid = blockIdx.x;                  // 0..767
    const int xcd = bid & 7, idx = bid >> 3;     // idx 0..95
    const int mbl = idx & 7, hh = idx >> 3;      // hh 0..11 (head)
    const int mb  = xcd * 8 + mbl;               // 0..63 row-panel
    const int b   = mb >> 3;
    const int nr0 = (mb & 7) * 128;
    const int n0  = hh * 64;

    const int tid = threadIdx.x, wv = tid >> 6, l = tid & 63;
    const int ln  = l & 31, half = l >> 5;

    f32x16 acc[2] = {};

    const int wsel = wv & 1;
    #define STAGE(kt_) do {                                                    \
        char* bufB = smem + ((kt_) & 1) * 24576;                               \
        if (wv < 2) {                                                          \
            _Pragma("unroll")                                                  \
            for (int p = 0; p < 8; ++p) {                                      \
                int chunk = wsel * 512 + p * 64 + l;                           \
                int r = chunk >> 3, s = chunk & 7;                             \
                int c = s ^ (r & 7);                                           \
                gl_lds16f(qf + ((size_t)((nr0 + r) * 8 + b)) * 768             \
                              + (kt_) * 32 + c * 4,                            \
                          bufB + chunk * 16);                                  \
            }                                                                  \
        } else {                                                               \
            _Pragma("unroll")                                                  \
            for (int p = 0; p < 4; ++p) {                                      \
                int chunk = wsel * 256 + p * 64 + l;                           \
                int r = chunk >> 3, s = chunk & 7;                             \
                int c = s ^ (r & 7);                                           \
                const ushort* src = (c < 4)                                    \
                    ? wh + (size_t)(n0 + r) * 768 + (kt_) * 32 + c * 8         \
                    : wl + (size_t)(n0 + r) * 768 + (kt_) * 32 + (c & 3) * 8;  \
                gl_lds16u(src, bufB + 16384 + chunk * 16);                     \
            }                                                                  \
        }                                                                      \
    } while (0)

    STAGE(0);
    __syncthreads();

    for (int kt = 0; kt < 24; ++kt) {
        if (kt + 1 < 24) STAGE(kt + 1);           // issue early: loads fly
        const char*   Ab = smem + (kt & 1) * 24576;
        const ushort* Bb = (const ushort*)(Ab + 16384);

        #pragma unroll
        for (int ks = 0; ks < 2; ++ks) {
            const int cc = ks * 2 + half;         // bf16 k-chunk 0..3
            const int ra = wv * 32 + ln;
            uint4 a0 = *(const uint4*)(Ab + ra * 128 + (((cc * 2)     ^ (ra & 7)) * 16));
            uint4 a1 = *(const uint4*)(Ab + ra * 128 + (((cc * 2 + 1) ^ (ra & 7)) * 16));
            short8 a_h, a_l;
            split8(a0, a1, a_h, a_l);
            short8 b_h[2], b_l[2];
            #pragma unroll
            for (int ni = 0; ni < 2; ++ni) {
                int rb = ni * 32 + ln;
                b_h[ni] = *(const short8*)(Bb + rb * 64 + ((cc       ^ (rb & 7)) * 8));
                b_l[ni] = *(const short8*)(Bb + rb * 64 + (((cc + 4) ^ (rb & 7)) * 8));
            }
            #pragma unroll
            for (int ni = 0; ni < 2; ++ni) {
                acc[ni] = mfma32(a_h, b_h[ni], acc[ni]);
                acc[ni] = mfma32(a_h, b_l[ni], acc[ni]);
                acc[ni] = mfma32(a_l, b_h[ni], acc[ni]);
            }
        }
        __syncthreads();                          // reads done + next stage landed
    }
    #undef STAGE

    // ---- epilogue: C tile -> LDS [128][68] f32, norms, vn + vt ----
    float* Ct = (float*)smem;                     // 128*68*4 = 34816 B
    #pragma unroll
    for (int ni = 0; ni < 2; ++ni)
        #pragma unroll
        for (int i = 0; i < 16; ++i) {
            int row = wv * 32 + (i & 3) + 8 * (i >> 2) + 4 * half;
            Ct[row * 68 + ni * 32 + ln] = acc[ni][i];
        }
    __syncthreads();

    const int bhn = b * NH + hh;
    {   // vn: thread t -> row t>>1, 32-col part t&1 (pair-reduce via shfl)
        int r = tid >> 1, part = tid & 1;
        const float* src = Ct + r * 68 + part * 32;
        float ss = 0.f;
        #pragma unroll
        for (int j = 0; j < 8; ++j) {
            float4 v4 = *(const float4*)(src + j * 4);
            ss += v4.x * v4.x + v4.y * v4.y + v4.z * v4.z + v4.w * v4.w;
        }
        ss += __shfl_xor(ss, 1);
        float rn = rsqrtf(ss) * SQRT_CS;          // fold softmax scale into vn
        ushort* dst = vn + ((size_t)bhn * NTOK + nr0 + r) * HD + part * 32;
        #pragma unroll
        for (int q8 = 0; q8 < 4; ++q8) {
            float4 u0 = *(const float4*)(src + q8 * 8);
            float4 u1 = *(const float4*)(src + q8 * 8 + 4);
            ushort8 o;
            o[0] = f2bf(u0.x * rn); o[1] = f2bf(u0.y * rn);
            o[2] = f2bf(u0.z * rn); o[3] = f2bf(u0.w * rn);
            o[4] = f2bf(u1.x * rn); o[5] = f2bf(u1.y * rn);
            o[6] = f2bf(u1.z * rn); o[7] = f2bf(u1.w * rn);
            *(ushort8*)(dst + q8 * 8) = o;
        }
    }
    {   // vt: thread t -> col d = t&63, 32-row segment seg = t>>6
        int d = tid & 63, seg = tid >> 6;
        ushort* dst = vt + ((size_t)bhn * HD + d) * NTOK + nr0 + seg * 32;
        #pragma unroll
        for (int q8 = 0; q8 < 4; ++q8) {
            ushort8 o;
            #pragma unroll
            for (int j = 0; j < 8; ++j)
                o[j] = f2bf(Ct[(seg * 32 + q8 * 8 + j) * 68 + d]);
            *(ushort8*)(dst + q8 * 8) = o;
        }
    }
}

// ---------------------------------------------------------------------------
// Fallback vproj (all-in-register split, single-buffered) if ws too small.
// ---------------------------------------------------------------------------
__global__ __launch_bounds__(256) void vproj_mfma_irs_kernel(
    const float* __restrict__ qf, const float* __restrict__ wf,
    ushort* __restrict__ vn, ushort* __restrict__ vt)
{
    __shared__ __align__(16) char smem[49152];
    char* Ae = smem;
    char* Ao = smem + 16384;
    char* Be = smem + 32768;
    char* Bo = smem + 40960;

    const int bid = blockIdx.x;
    const int xcd = bid & 7, idx = bid >> 3;
    const int mbl = idx & 7, hh = idx >> 3;
    const int mb  = xcd * 8 + mbl;
    const int b   = mb >> 3;
    const int nr0 = (mb & 7) * 128;
    const int n0  = hh * 64;

    const int tid = threadIdx.x, wv = tid >> 6, l = tid & 63;
    const int ln  = l & 31, half = l >> 5;

    f32x16 acc[2] = {};

    for (int kt = 0; kt < 12; ++kt) {
        __syncthreads();
        if (wv < 2) {
            char* dstT = wv ? Ao : Ae;
            const int kofs = kt * 64 + wv * 32;
            #pragma unroll
            for (int p = 0; p < 16; ++p) {
                int chunk = p * 64 + l;
                int r = chunk >> 3, c = chunk & 7;
                int csrc = c ^ (r & 7);
                gl_lds16f(qf + ((size_t)((nr0 + r) * 8 + b)) * 768 + kofs + csrc * 4,
                          dstT + p * 1024);
            }
        } else {
            char* dstT = (wv == 3) ? Bo : Be;
            const int kofs = kt * 64 + (wv == 3 ? 32 : 0);
            #pragma unroll
            for (int p = 0; p < 8; ++p) {
                int chunk = p * 64 + l;
                int r = chunk >> 3, c = chunk & 7;
                int csrc = c ^ (r & 7);
                gl_lds16f(wf + (size_t)(n0 + r) * 768 + kofs + csrc * 4,
                          dstT + p * 1024);
            }
        }
        __syncthreads();

        #pragma unroll
        for (int ks = 0; ks < 4; ++ks) {
            const int cc  = ks * 2 + half;
            const int cc2 = (cc & 3) * 2;
            const int ra  = wv * 32 + ln;
            const char* At = (cc < 4) ? Ae : Ao;
            uint4 a0 = *(const uint4*)(At + ra * 128 + ((cc2 ^ (ra & 7)) * 16));
            uint4 a1 = *(const uint4*)(At + ra * 128 + (((cc2 + 1) ^ (ra & 7)) * 16));
            short8 a_h, a_l;
            split8(a0, a1, a_h, a_l);
            short8 b_h[2], b_l[2];
            const char* Bt = (cc < 4) ? Be : Bo;
            #pragma unroll
            for (int ni = 0; ni < 2; ++ni) {
                int rb = ni * 32 + ln;
                uint4 b0 = *(const uint4*)(Bt + rb * 128 + ((cc2 ^ (rb & 7)) * 16));
                uint4 b1 = *(const uint4*)(Bt + rb * 128 + (((cc2 + 1) ^ (rb & 7)) * 16));
                split8(b0, b1, b_h[ni], b_l[ni]);
            }
            #pragma unroll
            for (int ni = 0; ni < 2; ++ni) {
                acc[ni] = mfma32(a_h, b_h[ni], acc[ni]);
                acc[ni] = mfma32(a_h, b_l[ni], acc[ni]);
                acc[ni] = mfma32(a_l, b_h[ni], acc[ni]);
            }
        }
    }

    __syncthreads();
    float* Ct = (float*)smem;
    #pragma unroll
    for (int ni = 0; ni < 2; ++ni)
        #pragma unroll
        for (int i = 0; i < 16; ++i) {
            int row = wv * 32 + (i & 3) + 8 * (i >> 2) + 4 * half;
            Ct[row * 68 + ni * 32 + ln] = acc[ni][i];
        }
    __syncthreads();

    const int bhn = b * NH + hh;
    {
        int r = tid >> 1, part = tid & 1;
        const float* src = Ct + r * 68 + part * 32;
        float ss = 0.f;
        #pragma unroll
        for (int j = 0; j < 8; ++j) {
            float4 v4 = *(const float4*)(src + j * 4);
            ss += v4.x * v4.x + v4.y * v4.y + v4.z * v4.z + v4.w * v4.w;
        }
        ss += __shfl_xor(ss, 1);
        float rn = rsqrtf(ss) * SQRT_CS;
        ushort* dst = vn + ((size_t)bhn * NTOK + nr0 + r) * HD + part * 32;
        #pragma unroll
        for (int q8 = 0; q8 < 4; ++q8) {
            float4 u0 = *(const float4*)(src + q8 * 8);
            float4 u1 = *(const float4*)(src + q8 * 8 + 4);
            ushort8 o;
            o[0] = f2bf(u0.x * rn); o[1] = f2bf(u0.y * rn);
            o[2] = f2bf(u0.z * rn); o[3] = f2bf(u0.w * rn);
            o[4] = f2bf(u1.x * rn); o[5] = f2bf(u1.y * rn);
            o[6] = f2bf(u1.z * rn); o[7] = f2bf(u1.w * rn);
            *(ushort8*)(dst + q8 * 8) = o;
        }
    }
    {
        int d = tid & 63, seg = tid >> 6;
        ushort* dst = vt + ((size_t)bhn * HD + d) * NTOK + nr0 + seg * 32;
        #pragma unroll
        for (int q8 = 0; q8 < 4; ++q8) {
            ushort8 o;
            #pragma unroll
            for (int j = 0; j < 8; ++j)
                o[j] = f2bf(Ct[(seg * 32 + q8 * 8 + j) * 68 + d]);
            *(ushort8*)(dst + q8 * 8) = o;
        }
    }
}

// ---------------------------------------------------------------------------
// Kernel 2: flash attention — round-20 best-measured version: 4 waves,
// Q-tile 128, single-barrier double-buffered K/V LDS, group-pipelined
// softmax/PV, bounded-logit softmax (scale folded into vn), XCD-pinned.
// ---------------------------------------------------------------------------
__global__ __launch_bounds__(256) void attn_kernel(
    const ushort* __restrict__ vn, const ushort* __restrict__ vt,
    float* __restrict__ out)
{
    __shared__ __align__(16) ushort Klds[2][64 * 64];   // [kv][d], swizzled
    __shared__ __align__(16) ushort Vlds[2][64 * 64];   // [d][kv], swizzled
    const int sblk = blockIdx.x;                 // 0..767
    const int tt   = sblk >> 3;
    const int bh   = (sblk & 7) + 8 * (tt >> 3); // XCD(bid%8) == bh%8
    const int q0   = (tt & 7) * 128;
    const int tid = threadIdx.x;
    const int wv  = tid >> 6;
    const int l   = tid & 63;
    const int ql  = l & 31;          // q column (one q-row per lane)
    const int h   = l >> 5;          // half

    const ushort* vb  = vn + (size_t)bh * NTOK * HD;
    const ushort* vtb = vt + (size_t)bh * HD * NTOK;

    short8 qB[4];
    {
        int qrow = q0 + wv * 32 + ql;
        #pragma unroll
        for (int ks = 0; ks < 4; ++ks)
            qB[ks] = *(const short8*)(vb + (size_t)qrow * HD + ks * 16 + h * 8);
    }

    const int sr0 = tid >> 3, sr1 = sr0 + 32;
    const int sc  = tid & 7;
    const int slt = (sc ^ (sr0 & 7)) * 8;        // sr1&7 == sr0&7
    uint4 kreg0, kreg1, vreg0, vreg1;

    f32x16 oT[2] = {};
    float l_acc = 0.f;

    kreg0 = *(const uint4*)(vb + (size_t)sr0 * HD + sc * 8);
    kreg1 = *(const uint4*)(vb + (size_t)sr1 * HD + sc * 8);
    vreg0 = *(const uint4*)(vtb + (size_t)sr0 * NTOK + sc * 8);
    vreg1 = *(const uint4*)(vtb + (size_t)sr1 * NTOK + sc * 8);
    *(uint4*)(&Klds[0][0] + sr0 * 64 + slt) = kreg0;
    *(uint4*)(&Klds[0][0] + sr1 * 64 + slt) = kreg1;
    *(uint4*)(&Vlds[0][0] + sr0 * 64 + slt) = vreg0;
    *(uint4*)(&Vlds[0][0] + sr1 * 64 + slt) = vreg1;
    __syncthreads();

    for (int kt = 0; kt < NTOK / 64; ++kt) {
        const int cur = kt & 1;
        const ushort* Kb = &Klds[cur][0];
        const ushort* Vb = &Vlds[cur][0];

        // T14: issue next tile's global loads early (land during compute)
        if (kt < NTOK / 64 - 1) {
            int kb = (kt + 1) * 64;
            kreg0 = *(const uint4*)(vb + (size_t)(kb + sr0) * HD + sc * 8);
            kreg1 = *(const uint4*)(vb + (size_t)(kb + sr1) * HD + sc * 8);
            vreg0 = *(const uint4*)(vtb + (size_t)sr0 * NTOK + kb + sc * 8);
            vreg1 = *(const uint4*)(vtb + (size_t)sr1 * NTOK + kb + sc * 8);
        }

        // QK^T: both 32-kv groups (chains interleave freely)
        f32x16 st[2] = {};
        #pragma unroll
        for (int ks = 0; ks < 4; ++ks) {
            int so = ((2 * ks + h) ^ (ql & 7)) * 8;
            short8 k0 = *(const short8*)(Kb + ql * 64 + so);
            short8 k1 = *(const short8*)(Kb + (32 + ql) * 64 + so);
            st[0] = mfma32(k0, qB[ks], st[0]);
            st[1] = mfma32(k1, qB[ks], st[1]);
        }

        // per group: exp2 -> sum -> pack -> PV  (group 1's VALU overlaps
        // group 0's PV MFMAs)
        #pragma unroll
        for (int g = 0; g < 2; ++g) {
            #pragma unroll
            for (int i = 0; i < 16; ++i)
                st[g][i] = __builtin_amdgcn_exp2f(st[g][i]);

            float ts[8];
            #pragma unroll
            for (int i = 0; i < 8; ++i) ts[i] = st[g][i] + st[g][i + 8];
            #pragma unroll
            for (int s = 4; s >= 1; s >>= 1)
                #pragma unroll
                for (int i = 0; i < s; ++i) ts[i] += ts[i + s];
            l_acc += ts[0];

            unsigned pb2[4][2];
            #pragma unroll
            for (int t = 0; t < 4; ++t)
                #pragma unroll
                for (int u = 0; u < 2; ++u)
                    asm("v_cvt_pk_bf16_f32 %0, %1, %2"
                        : "=v"(pb2[t][u])
                        : "v"(st[g][4 * t + 2 * u]), "v"(st[g][4 * t + 2 * u + 1]));

            #pragma unroll
            for (int sp = 0; sp < 2; ++sp) {
                const int s = g * 2 + sp;
                unsigned x0 = pb2[2 * sp][0], y0 = pb2[2 * sp + 1][0];
                unsigned x1 = pb2[2 * sp][1], y1 = pb2[2 * sp + 1][1];
                asm volatile("v_permlane32_swap_b32 %0, %1" : "+v"(x0), "+v"(y0));
                asm volatile("v_permlane32_swap_b32 %0, %1" : "+v"(x1), "+v"(y1));
                union { unsigned u[4]; short8 s8; } pb;
                pb.u[0] = x0; pb.u[1] = x1; pb.u[2] = y0; pb.u[3] = y1;
                int so = ((2 * s + h) ^ (ql & 7)) * 8;
                short8 v0 = *(const short8*)(Vb + ql * 64 + so);
                short8 v1 = *(const short8*)(Vb + (32 + ql) * 64 + so);
                oT[0] = mfma32(v0, pb.s8, oT[0]);
                oT[1] = mfma32(v1, pb.s8, oT[1]);
            }
        }

        // write next tile into the alternate buffer, ONE barrier per tile
        if (kt < NTOK / 64 - 1) {
            *(uint4*)(&Klds[cur ^ 1][0] + sr0 * 64 + slt) = kreg0;
            *(uint4*)(&Klds[cur ^ 1][0] + sr1 * 64 + slt) = kreg1;
            *(uint4*)(&Vlds[cur ^ 1][0] + sr0 * 64 + slt) = vreg0;
            *(uint4*)(&Vlds[cur ^ 1][0] + sr1 * 64 + slt) = vreg1;
            __syncthreads();
        }
    }

    const int b = bh / NH, hh = bh % NH;
    float lsum = l_acc + __shfl_xor(l_acc, 32);
    const float inv = 1.f / lsum;
    int n = q0 + wv * 32 + ql;
    float* orow = out + ((size_t)n * BATCH + b) * DM + hh * HD;
    #pragma unroll
    for (int dm = 0; dm < 2; ++dm)
        #pragma unroll
        for (int t = 0; t < 4; ++t) {
            float4 val = make_float4(oT[dm][4 * t] * inv, oT[dm][4 * t + 1] * inv,
                                     oT[dm][4 * t + 2] * inv, oT[dm][4 * t + 3] * inv);
            *(float4*)(orow + dm * 32 + t * 8 + h * 4) = val;
        }
}

extern "C" void kernel_launch(void* const* d_in, const int* in_sizes, int n_in,
                              void* d_out, int out_size, void* d_ws, size_t ws_size,
                              hipStream_t stream) {
    const float* q = (const float*)d_in[0];   // [1024, 8, 768]
    const float* w = (const float*)d_in[1];   // [768, 768]
    float* out = (float*)d_out;               // [1024, 8, 768]

    const size_t VE = (size_t)NH * BATCH * NTOK * HD;  // 6,291,456
    const size_t WE = (size_t)DM * DM;                 //   589,824
    ushort* vn = (ushort*)d_ws;                        // [96][1024][64] bf16
    ushort* vt = vn + VE;                              // [96][64][1024] bf16
    ushort* wh = vt + VE;
    ushort* wl = wh + WE;
    size_t need = (2 * VE + 2 * WE) * sizeof(ushort);

    if (ws_size >= need) {
        split_w_kernel<<<(WE / 8 + 255) / 256, 256, 0, stream>>>(w, wh, wl);
        vproj_mfma_kernel<<<768, 256, 0, stream>>>(q, wh, wl, vn, vt);
    } else {
        vproj_mfma_irs_kernel<<<768, 256, 0, stream>>>(q, w, vn, vt);
    }
    attn_kernel<<<NTOK / 128 * BATCH * NH, 256, 0, stream>>>(vn, vt, out);
}

// Round 25
// 89.299 us; speedup vs baseline: 1.4498x; 1.0006x over previous
//
#include <hip/hip_runtime.h>
#include <hip/hip_bf16.h>

#define NH    12
#define HD    64
#define NTOK  1024
#define BATCH 8
#define DM    768

typedef short  short8  __attribute__((ext_vector_type(8)));
typedef float  f32x4   __attribute__((ext_vector_type(4)));
typedef float  f32x16  __attribute__((ext_vector_type(16)));
typedef unsigned short ushort8 __attribute__((ext_vector_type(8)));

// sqrt(0.125 * log2(e)) — pre-scales vn so QK^T yields CS*cos directly
#define SQRT_CS 0.42466056f

__device__ __forceinline__ ushort f2bf(float f) {
    union { float f; unsigned u; } x; x.f = f;
    unsigned r = x.u + 0x7FFF + ((x.u >> 16) & 1);   // RNE
    return (ushort)(r >> 16);
}
__device__ __forceinline__ float bf2f(ushort h) {
    union { unsigned u; float f; } x; x.u = ((unsigned)h) << 16;
    return x.f;
}
__device__ __forceinline__ void gl_lds16f(const float* g, char* l) {
    __builtin_amdgcn_global_load_lds(
        (const __attribute__((address_space(1))) unsigned int*)g,
        (__attribute__((address_space(3))) unsigned int*)l, 16, 0, 0);
}
__device__ __forceinline__ void gl_lds16u(const ushort* g, char* l) {
    __builtin_amdgcn_global_load_lds(
        (const __attribute__((address_space(1))) unsigned int*)g,
        (__attribute__((address_space(3))) unsigned int*)l, 16, 0, 0);
}
__device__ __forceinline__ f32x16 mfma32(short8 a, short8 b, f32x16 c) {
    return __builtin_amdgcn_mfma_f32_32x32x16_bf16(a, b, c, 0, 0, 0);
}

// in-register split: 8 fp32 (two uint4) -> hi bf16x8 + lo bf16x8 (RNE, bit-
// identical to the split kernels: hi = bf16(x), lo = bf16(x - hi)).
__device__ __forceinline__ void split8(uint4 c0, uint4 c1,
                                       short8& hi8, short8& lo8) {
    const unsigned xs[8] = {c0.x, c0.y, c0.z, c0.w, c1.x, c1.y, c1.z, c1.w};
    union { unsigned u[4]; short8 s; } H, L;
    #pragma unroll
    for (int j = 0; j < 4; ++j) {
        float a0 = __uint_as_float(xs[2 * j]);
        float a1 = __uint_as_float(xs[2 * j + 1]);
        unsigned hp;
        asm("v_cvt_pk_bf16_f32 %0, %1, %2" : "=v"(hp) : "v"(a0), "v"(a1));
        float l0 = a0 - __uint_as_float(hp << 16);
        float l1 = a1 - __uint_as_float(hp & 0xFFFF0000u);
        unsigned lp;
        asm("v_cvt_pk_bf16_f32 %0, %1, %2" : "=v"(lp) : "v"(l0), "v"(l1));
        H.u[j] = hp; L.u[j] = lp;
    }
    hi8 = H.s; lo8 = L.s;
}

// ---------------------------------------------------------------------------
// split_w: w -> (hi, lo) bf16. Tiny (2.25 MB traffic).
// ---------------------------------------------------------------------------
__global__ __launch_bounds__(256) void split_w_kernel(
    const float* __restrict__ src, ushort* __restrict__ hi, ushort* __restrict__ lo)
{
    int t = blockIdx.x * 256 + threadIdx.x;       // 73728 threads
    if (t >= (DM * DM) / 8) return;
    const float* s = src + (size_t)t * 8;
    float4 x0 = *(const float4*)s, x1 = *(const float4*)(s + 4);
    float xs[8] = {x0.x, x0.y, x0.z, x0.w, x1.x, x1.y, x1.z, x1.w};
    ushort8 h8, l8;
    #pragma unroll
    for (int j = 0; j < 8; ++j) {
        ushort h = f2bf(xs[j]);
        h8[j] = h;
        l8[j] = f2bf(xs[j] - bf2f(h));
    }
    size_t o = (size_t)t * 8;
    *(ushort8*)(hi + o) = h8;
    *(ushort8*)(lo + o) = l8;
}

// ---------------------------------------------------------------------------
// vproj (hybrid split + 2-phase dbuf, round-19 version — best measured).
// ---------------------------------------------------------------------------
__global__ __launch_bounds__(256) void vproj_mfma_kernel(
    const float* __restrict__ qf,
    const ushort* __restrict__ wh, const ushort* __restrict__ wl,
    ushort* __restrict__ vn, ushort* __restrict__ vt)
{
    __shared__ __align__(16) char smem[49152];   // 2 x 24 KB
    const int bid = blockIdx.x;                  // 0..767
    const int xcd = bid & 7, idx = bid >> 3;     // idx 0..95
    const int mbl = idx & 7, hh = idx >> 3;      // hh 0..11 (head)
    const int mb  = xcd * 8 + mbl;               // 0..63 row-panel
    const int b   = mb >> 3;
    const int nr0 = (mb & 7) * 128;
    const int n0  = hh * 64;

    const int tid = threadIdx.x, wv = tid >> 6, l = tid & 63;
    const int ln  = l & 31, half = l >> 5;

    f32x16 acc[2] = {};

    const int wsel = wv & 1;
    #define STAGE(kt_) do {                                                    \
        char* bufB = smem + ((kt_) & 1) * 24576;                               \
        if (wv < 2) {                                                          \
            _Pragma("unroll")                                                  \
            for (int p = 0; p < 8; ++p) {                                      \
                int chunk = wsel * 512 + p * 64 + l;                           \
                int r = chunk >> 3, s = chunk & 7;                             \
                int c = s ^ (r & 7);                                           \
                gl_lds16f(qf + ((size_t)((nr0 + r) * 8 + b)) * 768             \
                              + (kt_) * 32 + c * 4,                            \
                          bufB + chunk * 16);                                  \
            }                                                                  \
        } else {                                                               \
            _Pragma("unroll")                                                  \
            for (int p = 0; p < 4; ++p) {                                      \
                int chunk = wsel * 256 + p * 64 + l;                           \
                int r = chunk >> 3, s = chunk & 7;                             \
                int c = s ^ (r & 7);                                           \
                const ushort* src = (c < 4)                                    \
                    ? wh + (size_t)(n0 + r) * 768 + (kt_) * 32 + c * 8         \
                    : wl + (size_t)(n0 + r) * 768 + (kt_) * 32 + (c & 3) * 8;  \
                gl_lds16u(src, bufB + 16384 + chunk * 16);                     \
            }                                                                  \
        }                                                                      \
    } while (0)

    STAGE(0);
    __syncthreads();

    for (int kt = 0; kt < 24; ++kt) {
        if (kt + 1 < 24) STAGE(kt + 1);           // issue early: loads fly
        const char*   Ab = smem + (kt & 1) * 24576;
        const ushort* Bb = (const ushort*)(Ab + 16384);

        #pragma unroll
        for (int ks = 0; ks < 2; ++ks) {
            const int cc = ks * 2 + half;         // bf16 k-chunk 0..3
            const int ra = wv * 32 + ln;
            uint4 a0 = *(const uint4*)(Ab + ra * 128 + (((cc * 2)     ^ (ra & 7)) * 16));
            uint4 a1 = *(const uint4*)(Ab + ra * 128 + (((cc * 2 + 1) ^ (ra & 7)) * 16));
            short8 a_h, a_l;
            split8(a0, a1, a_h, a_l);
            short8 b_h[2], b_l[2];
            #pragma unroll
            for (int ni = 0; ni < 2; ++ni) {
                int rb = ni * 32 + ln;
                b_h[ni] = *(const short8*)(Bb + rb * 64 + ((cc       ^ (rb & 7)) * 8));
                b_l[ni] = *(const short8*)(Bb + rb * 64 + (((cc + 4) ^ (rb & 7)) * 8));
            }
            #pragma unroll
            for (int ni = 0; ni < 2; ++ni) {
                acc[ni] = mfma32(a_h, b_h[ni], acc[ni]);
                acc[ni] = mfma32(a_h, b_l[ni], acc[ni]);
                acc[ni] = mfma32(a_l, b_h[ni], acc[ni]);
            }
        }
        __syncthreads();                          // reads done + next stage landed
    }
    #undef STAGE

    // ---- epilogue: C tile -> LDS [128][68] f32, norms, vn + vt ----
    float* Ct = (float*)smem;                     // 128*68*4 = 34816 B
    #pragma unroll
    for (int ni = 0; ni < 2; ++ni)
        #pragma unroll
        for (int i = 0; i < 16; ++i) {
            int row = wv * 32 + (i & 3) + 8 * (i >> 2) + 4 * half;
            Ct[row * 68 + ni * 32 + ln] = acc[ni][i];
        }
    __syncthreads();

    const int bhn = b * NH + hh;
    {   // vn: thread t -> row t>>1, 32-col part t&1 (pair-reduce via shfl)
        int r = tid >> 1, part = tid & 1;
        const float* src = Ct + r * 68 + part * 32;
        float ss = 0.f;
        #pragma unroll
        for (int j = 0; j < 8; ++j) {
            float4 v4 = *(const float4*)(src + j * 4);
            ss += v4.x * v4.x + v4.y * v4.y + v4.z * v4.z + v4.w * v4.w;
        }
        ss += __shfl_xor(ss, 1);
        float rn = rsqrtf(ss) * SQRT_CS;          // fold softmax scale into vn
        ushort* dst = vn + ((size_t)bhn * NTOK + nr0 + r) * HD + part * 32;
        #pragma unroll
        for (int q8 = 0; q8 < 4; ++q8) {
            float4 u0 = *(const float4*)(src + q8 * 8);
            float4 u1 = *(const float4*)(src + q8 * 8 + 4);
            ushort8 o;
            o[0] = f2bf(u0.x * rn); o[1] = f2bf(u0.y * rn);
            o[2] = f2bf(u0.z * rn); o[3] = f2bf(u0.w * rn);
            o[4] = f2bf(u1.x * rn); o[5] = f2bf(u1.y * rn);
            o[6] = f2bf(u1.z * rn); o[7] = f2bf(u1.w * rn);
            *(ushort8*)(dst + q8 * 8) = o;
        }
    }
    {   // vt: thread t -> col d = t&63, 32-row segment seg = t>>6
        int d = tid & 63, seg = tid >> 6;
        ushort* dst = vt + ((size_t)bhn * HD + d) * NTOK + nr0 + seg * 32;
        #pragma unroll
        for (int q8 = 0; q8 < 4; ++q8) {
            ushort8 o;
            #pragma unroll
            for (int j = 0; j < 8; ++j)
                o[j] = f2bf(Ct[(seg * 32 + q8 * 8 + j) * 68 + d]);
            *(ushort8*)(dst + q8 * 8) = o;
        }
    }
}

// ---------------------------------------------------------------------------
// Fallback vproj (all-in-register split, single-buffered) if ws too small.
// ---------------------------------------------------------------------------
__global__ __launch_bounds__(256) void vproj_mfma_irs_kernel(
    const float* __restrict__ qf, const float* __restrict__ wf,
    ushort* __restrict__ vn, ushort* __restrict__ vt)
{
    __shared__ __align__(16) char smem[49152];
    char* Ae = smem;
    char* Ao = smem + 16384;
    char* Be = smem + 32768;
    char* Bo = smem + 40960;

    const int bid = blockIdx.x;
    const int xcd = bid & 7, idx = bid >> 3;
    const int mbl = idx & 7, hh = idx >> 3;
    const int mb  = xcd * 8 + mbl;
    const int b   = mb >> 3;
    const int nr0 = (mb & 7) * 128;
    const int n0  = hh * 64;

    const int tid = threadIdx.x, wv = tid >> 6, l = tid & 63;
    const int ln  = l & 31, half = l >> 5;

    f32x16 acc[2] = {};

    for (int kt = 0; kt < 12; ++kt) {
        __syncthreads();
        if (wv < 2) {
            char* dstT = wv ? Ao : Ae;
            const int kofs = kt * 64 + wv * 32;
            #pragma unroll
            for (int p = 0; p < 16; ++p) {
                int chunk = p * 64 + l;
                int r = chunk >> 3, c = chunk & 7;
                int csrc = c ^ (r & 7);
                gl_lds16f(qf + ((size_t)((nr0 + r) * 8 + b)) * 768 + kofs + csrc * 4,
                          dstT + p * 1024);
            }
        } else {
            char* dstT = (wv == 3) ? Bo : Be;
            const int kofs = kt * 64 + (wv == 3 ? 32 : 0);
            #pragma unroll
            for (int p = 0; p < 8; ++p) {
                int chunk = p * 64 + l;
                int r = chunk >> 3, c = chunk & 7;
                int csrc = c ^ (r & 7);
                gl_lds16f(wf + (size_t)(n0 + r) * 768 + kofs + csrc * 4,
                          dstT + p * 1024);
            }
        }
        __syncthreads();

        #pragma unroll
        for (int ks = 0; ks < 4; ++ks) {
            const int cc  = ks * 2 + half;
            const int cc2 = (cc & 3) * 2;
            const int ra  = wv * 32 + ln;
            const char* At = (cc < 4) ? Ae : Ao;
            uint4 a0 = *(const uint4*)(At + ra * 128 + ((cc2 ^ (ra & 7)) * 16));
            uint4 a1 = *(const uint4*)(At + ra * 128 + (((cc2 + 1) ^ (ra & 7)) * 16));
            short8 a_h, a_l;
            split8(a0, a1, a_h, a_l);
            short8 b_h[2], b_l[2];
            const char* Bt = (cc < 4) ? Be : Bo;
            #pragma unroll
            for (int ni = 0; ni < 2; ++ni) {
                int rb = ni * 32 + ln;
                uint4 b0 = *(const uint4*)(Bt + rb * 128 + ((cc2 ^ (rb & 7)) * 16));
                uint4 b1 = *(const uint4*)(Bt + rb * 128 + (((cc2 + 1) ^ (rb & 7)) * 16));
                split8(b0, b1, b_h[ni], b_l[ni]);
            }
            #pragma unroll
            for (int ni = 0; ni < 2; ++ni) {
                acc[ni] = mfma32(a_h, b_h[ni], acc[ni]);
                acc[ni] = mfma32(a_h, b_l[ni], acc[ni]);
                acc[ni] = mfma32(a_l, b_h[ni], acc[ni]);
            }
        }
    }

    __syncthreads();
    float* Ct = (float*)smem;
    #pragma unroll
    for (int ni = 0; ni < 2; ++ni)
        #pragma unroll
        for (int i = 0; i < 16; ++i) {
            int row = wv * 32 + (i & 3) + 8 * (i >> 2) + 4 * half;
            Ct[row * 68 + ni * 32 + ln] = acc[ni][i];
        }
    __syncthreads();

    const int bhn = b * NH + hh;
    {
        int r = tid >> 1, part = tid & 1;
        const float* src = Ct + r * 68 + part * 32;
        float ss = 0.f;
        #pragma unroll
        for (int j = 0; j < 8; ++j) {
            float4 v4 = *(const float4*)(src + j * 4);
            ss += v4.x * v4.x + v4.y * v4.y + v4.z * v4.z + v4.w * v4.w;
        }
        ss += __shfl_xor(ss, 1);
        float rn = rsqrtf(ss) * SQRT_CS;
        ushort* dst = vn + ((size_t)bhn * NTOK + nr0 + r) * HD + part * 32;
        #pragma unroll
        for (int q8 = 0; q8 < 4; ++q8) {
            float4 u0 = *(const float4*)(src + q8 * 8);
            float4 u1 = *(const float4*)(src + q8 * 8 + 4);
            ushort8 o;
            o[0] = f2bf(u0.x * rn); o[1] = f2bf(u0.y * rn);
            o[2] = f2bf(u0.z * rn); o[3] = f2bf(u0.w * rn);
            o[4] = f2bf(u1.x * rn); o[5] = f2bf(u1.y * rn);
            o[6] = f2bf(u1.z * rn); o[7] = f2bf(u1.w * rn);
            *(ushort8*)(dst + q8 * 8) = o;
        }
    }
    {
        int d = tid & 63, seg = tid >> 6;
        ushort* dst = vt + ((size_t)bhn * HD + d) * NTOK + nr0 + seg * 32;
        #pragma unroll
        for (int q8 = 0; q8 < 4; ++q8) {
            ushort8 o;
            #pragma unroll
            for (int j = 0; j < 8; ++j)
                o[j] = f2bf(Ct[(seg * 32 + q8 * 8 + j) * 68 + d]);
            *(ushort8*)(dst + q8 * 8) = o;
        }
    }
}

// ---------------------------------------------------------------------------
// Kernel 2: flash attention — round-20 best-measured version: 4 waves,
// Q-tile 128, single-barrier double-buffered K/V LDS, group-pipelined
// softmax/PV, bounded-logit softmax (scale folded into vn), XCD-pinned.
// ---------------------------------------------------------------------------
__global__ __launch_bounds__(256) void attn_kernel(
    const ushort* __restrict__ vn, const ushort* __restrict__ vt,
    float* __restrict__ out)
{
    __shared__ __align__(16) ushort Klds[2][64 * 64];   // [kv][d], swizzled
    __shared__ __align__(16) ushort Vlds[2][64 * 64];   // [d][kv], swizzled
    const int sblk = blockIdx.x;                 // 0..767
    const int tt   = sblk >> 3;
    const int bh   = (sblk & 7) + 8 * (tt >> 3); // XCD(bid%8) == bh%8
    const int q0   = (tt & 7) * 128;
    const int tid = threadIdx.x;
    const int wv  = tid >> 6;
    const int l   = tid & 63;
    const int ql  = l & 31;          // q column (one q-row per lane)
    const int h   = l >> 5;          // half

    const ushort* vb  = vn + (size_t)bh * NTOK * HD;
    const ushort* vtb = vt + (size_t)bh * HD * NTOK;

    short8 qB[4];
    {
        int qrow = q0 + wv * 32 + ql;
        #pragma unroll
        for (int ks = 0; ks < 4; ++ks)
            qB[ks] = *(const short8*)(vb + (size_t)qrow * HD + ks * 16 + h * 8);
    }

    const int sr0 = tid >> 3, sr1 = sr0 + 32;
    const int sc  = tid & 7;
    const int slt = (sc ^ (sr0 & 7)) * 8;        // sr1&7 == sr0&7
    uint4 kreg0, kreg1, vreg0, vreg1;

    f32x16 oT[2] = {};
    float l_acc = 0.f;

    kreg0 = *(const uint4*)(vb + (size_t)sr0 * HD + sc * 8);
    kreg1 = *(const uint4*)(vb + (size_t)sr1 * HD + sc * 8);
    vreg0 = *(const uint4*)(vtb + (size_t)sr0 * NTOK + sc * 8);
    vreg1 = *(const uint4*)(vtb + (size_t)sr1 * NTOK + sc * 8);
    *(uint4*)(&Klds[0][0] + sr0 * 64 + slt) = kreg0;
    *(uint4*)(&Klds[0][0] + sr1 * 64 + slt) = kreg1;
    *(uint4*)(&Vlds[0][0] + sr0 * 64 + slt) = vreg0;
    *(uint4*)(&Vlds[0][0] + sr1 * 64 + slt) = vreg1;
    __syncthreads();

    for (int kt = 0; kt < NTOK / 64; ++kt) {
        const int cur = kt & 1;
        const ushort* Kb = &Klds[cur][0];
        const ushort* Vb = &Vlds[cur][0];

        // T14: issue next tile's global loads early (land during compute)
        if (kt < NTOK / 64 - 1) {
            int kb = (kt + 1) * 64;
            kreg0 = *(const uint4*)(vb + (size_t)(kb + sr0) * HD + sc * 8);
            kreg1 = *(const uint4*)(vb + (size_t)(kb + sr1) * HD + sc * 8);
            vreg0 = *(const uint4*)(vtb + (size_t)sr0 * NTOK + kb + sc * 8);
            vreg1 = *(const uint4*)(vtb + (size_t)sr1 * NTOK + kb + sc * 8);
        }

        // QK^T: both 32-kv groups (chains interleave freely)
        f32x16 st[2] = {};
        #pragma unroll
        for (int ks = 0; ks < 4; ++ks) {
            int so = ((2 * ks + h) ^ (ql & 7)) * 8;
            short8 k0 = *(const short8*)(Kb + ql * 64 + so);
            short8 k1 = *(const short8*)(Kb + (32 + ql) * 64 + so);
            st[0] = mfma32(k0, qB[ks], st[0]);
            st[1] = mfma32(k1, qB[ks], st[1]);
        }

        // per group: exp2 -> sum -> pack -> PV  (group 1's VALU overlaps
        // group 0's PV MFMAs)
        #pragma unroll
        for (int g = 0; g < 2; ++g) {
            #pragma unroll
            for (int i = 0; i < 16; ++i)
                st[g][i] = __builtin_amdgcn_exp2f(st[g][i]);

            float ts[8];
            #pragma unroll
            for (int i = 0; i < 8; ++i) ts[i] = st[g][i] + st[g][i + 8];
            #pragma unroll
            for (int s = 4; s >= 1; s >>= 1)
                #pragma unroll
                for (int i = 0; i < s; ++i) ts[i] += ts[i + s];
            l_acc += ts[0];

            unsigned pb2[4][2];
            #pragma unroll
            for (int t = 0; t < 4; ++t)
                #pragma unroll
                for (int u = 0; u < 2; ++u)
                    asm("v_cvt_pk_bf16_f32 %0, %1, %2"
                        : "=v"(pb2[t][u])
                        : "v"(st[g][4 * t + 2 * u]), "v"(st[g][4 * t + 2 * u + 1]));

            #pragma unroll
            for (int sp = 0; sp < 2; ++sp) {
                const int s = g * 2 + sp;
                unsigned x0 = pb2[2 * sp][0], y0 = pb2[2 * sp + 1][0];
                unsigned x1 = pb2[2 * sp][1], y1 = pb2[2 * sp + 1][1];
                asm volatile("v_permlane32_swap_b32 %0, %1" : "+v"(x0), "+v"(y0));
                asm volatile("v_permlane32_swap_b32 %0, %1" : "+v"(x1), "+v"(y1));
                union { unsigned u[4]; short8 s8; } pb;
                pb.u[0] = x0; pb.u[1] = x1; pb.u[2] = y0; pb.u[3] = y1;
                int so = ((2 * s + h) ^ (ql & 7)) * 8;
                short8 v0 = *(const short8*)(Vb + ql * 64 + so);
                short8 v1 = *(const short8*)(Vb + (32 + ql) * 64 + so);
                oT[0] = mfma32(v0, pb.s8, oT[0]);
                oT[1] = mfma32(v1, pb.s8, oT[1]);
            }
        }

        // write next tile into the alternate buffer, ONE barrier per tile
        if (kt < NTOK / 64 - 1) {
            *(uint4*)(&Klds[cur ^ 1][0] + sr0 * 64 + slt) = kreg0;
            *(uint4*)(&Klds[cur ^ 1][0] + sr1 * 64 + slt) = kreg1;
            *(uint4*)(&Vlds[cur ^ 1][0] + sr0 * 64 + slt) = vreg0;
            *(uint4*)(&Vlds[cur ^ 1][0] + sr1 * 64 + slt) = vreg1;
            __syncthreads();
        }
    }

    const int b = bh / NH, hh = bh % NH;
    float lsum = l_acc + __shfl_xor(l_acc, 32);
    const float inv = 1.f / lsum;
    int n = q0 + wv * 32 + ql;
    float* orow = out + ((size_t)n * BATCH + b) * DM + hh * HD;
    #pragma unroll
    for (int dm = 0; dm < 2; ++dm)
        #pragma unroll
        for (int t = 0; t < 4; ++t) {
            float4 val = make_float4(oT[dm][4 * t] * inv, oT[dm][4 * t + 1] * inv,
                                     oT[dm][4 * t + 2] * inv, oT[dm][4 * t + 3] * inv);
            *(float4*)(orow + dm * 32 + t * 8 + h * 4) = val;
        }
}

extern "C" void kernel_launch(void* const* d_in, const int* in_sizes, int n_in,
                              void* d_out, int out_size, void* d_ws, size_t ws_size,
                              hipStream_t stream) {
    const float* q = (const float*)d_in[0];   // [1024, 8, 768]
    const float* w = (const float*)d_in[1];   // [768, 768]
    float* out = (float*)d_out;               // [1024, 8, 768]

    const size_t VE = (size_t)NH * BATCH * NTOK * HD;  // 6,291,456
    const size_t WE = (size_t)DM * DM;                 //   589,824
    ushort* vn = (ushort*)d_ws;                        // [96][1024][64] bf16
    ushort* vt = vn + VE;                              // [96][64][1024] bf16
    ushort* wh = vt + VE;
    ushort* wl = wh + WE;
    size_t need = (2 * VE + 2 * WE) * sizeof(ushort);

    if (ws_size >= need) {
        split_w_kernel<<<(WE / 8 + 255) / 256, 256, 0, stream>>>(w, wh, wl);
        vproj_mfma_kernel<<<768, 256, 0, stream>>>(q, wh, wl, vn, vt);
    } else {
        vproj_mfma_irs_kernel<<<768, 256, 0, stream>>>(q, w, vn, vt);
    }
    attn_kernel<<<NTOK / 128 * BATCH * NH, 256, 0, stream>>>(vn, vt, out);
}